// Round 6
// baseline (1027.849 us; speedup 1.0000x reference)
//
#include <hip/hip_runtime.h>
#include <hip/hip_bf16.h>
#include <hip/hip_cooperative_groups.h>

namespace cg = cooperative_groups;

// Problem constants
constexpr int Bn  = 128;   // batch
constexpr int Ln  = 200;   // sentences
constexpr int D2n = 1024;  // 2*SH
constexpr int G3n = 1536;  // 3*EH
constexpr int Tn  = 3;
constexpr int Nn  = 512;   // A (attention dim) == d_proj cols
constexpr int Kn  = 1024;  // d_proj K

typedef unsigned short ushort;
typedef float f32x4 __attribute__((ext_vector_type(4)));
typedef __bf16 bf16x8 __attribute__((ext_vector_type(8)));

__device__ __forceinline__ ushort f2bf(float f) {   // RNE float->bf16
  unsigned u = __float_as_uint(f);
  unsigned r = (u + 0x7fffu + ((u >> 16) & 1u)) >> 16;
  return (ushort)r;
}
__device__ __forceinline__ float bf2f(ushort h) {
  return __uint_as_float(((unsigned)h) << 16);
}
__device__ __forceinline__ float fast_tanh(float x) {
  float ax = __builtin_fabsf(x);
  float e  = __expf(-2.f * ax);
  float t  = (1.f - e) / (1.f + e);
  return __builtin_copysignf(t, x);
}

// ---------------------------------------------------------------------------
// split W (fp32) into hi/lo bf16 (RNE, once, for wd)
__global__ void k_splitW(const float* __restrict__ W, ushort* __restrict__ hi,
                         ushort* __restrict__ lo) {
  int i = blockIdx.x * 256 + threadIdx.x;        // element/4
  float4 v = ((const float4*)W)[i];
  ushort4 h, l;
  h.x = f2bf(v.x); l.x = f2bf(v.x - bf2f(h.x));
  h.y = f2bf(v.y); l.y = f2bf(v.y - bf2f(h.y));
  h.z = f2bf(v.z); l.z = f2bf(v.z - bf2f(h.z));
  h.w = f2bf(v.w); l.w = f2bf(v.w - bf2f(h.w));
  ((ushort4*)hi)[i] = h;
  ((ushort4*)lo)[i] = l;
}

// ---------------------------------------------------------------------------
// d_proj = sent @ wd^T + bd  via split-bf16 MFMA (3 mfma, fp32 acc)
constexpr int LDW = 36;   // padded LDS row (shorts)
__launch_bounds__(256)
__global__ void k_dproj_mfma(const float* __restrict__ A, const ushort* __restrict__ Whi,
                             const ushort* __restrict__ Wlo, const float* __restrict__ bias,
                             float* __restrict__ C) {
  __shared__ __align__(16) ushort Ah[128][LDW];
  __shared__ __align__(16) ushort Al[128][LDW];
  __shared__ __align__(16) ushort Bh[128][LDW];
  __shared__ __align__(16) ushort Bl[128][LDW];

  const int m0 = blockIdx.x * 128, n0 = blockIdx.y * 128;
  const int tid  = threadIdx.x;
  const int wave = tid >> 6, lane = tid & 63;
  const int wy = (wave >> 1) * 64, wx = (wave & 1) * 64;
  const int lm = lane & 15, lq = lane >> 4;

  const int sr = tid >> 1;
  const int sk = (tid & 1) * 16;

  f32x4 acc[4][4] = {};

  const float* Arow = A + (size_t)(m0 + sr) * Kn + sk;
  const ushort* Bhrow = Whi + (size_t)(n0 + sr) * Kn + sk;
  const ushort* Blrow = Wlo + (size_t)(n0 + sr) * Kn + sk;

  for (int k0 = 0; k0 < Kn; k0 += 32) {
    #pragma unroll
    for (int i = 0; i < 4; ++i) {
      float4 v = *(const float4*)(Arow + k0 + i * 4);
      ushort4 h, l;
      unsigned u;
      u = __float_as_uint(v.x); h.x = (ushort)(u >> 16);
      l.x = (ushort)(__float_as_uint(v.x - __uint_as_float(u & 0xffff0000u)) >> 16);
      u = __float_as_uint(v.y); h.y = (ushort)(u >> 16);
      l.y = (ushort)(__float_as_uint(v.y - __uint_as_float(u & 0xffff0000u)) >> 16);
      u = __float_as_uint(v.z); h.z = (ushort)(u >> 16);
      l.z = (ushort)(__float_as_uint(v.z - __uint_as_float(u & 0xffff0000u)) >> 16);
      u = __float_as_uint(v.w); h.w = (ushort)(u >> 16);
      l.w = (ushort)(__float_as_uint(v.w - __uint_as_float(u & 0xffff0000u)) >> 16);
      *(ushort4*)&Ah[sr][sk + i * 4] = h;
      *(ushort4*)&Al[sr][sk + i * 4] = l;
    }
    #pragma unroll
    for (int i = 0; i < 2; ++i) {
      *(int4*)&Bh[sr][sk + i * 8] = *(const int4*)(Bhrow + k0 + i * 8);
      *(int4*)&Bl[sr][sk + i * 8] = *(const int4*)(Blrow + k0 + i * 8);
    }
    __syncthreads();

    bf16x8 ah[4], al[4], bh[4], bl[4];
    #pragma unroll
    for (int mi = 0; mi < 4; ++mi) {
      ah[mi] = *(const bf16x8*)&Ah[wy + mi * 16 + lm][lq * 8];
      al[mi] = *(const bf16x8*)&Al[wy + mi * 16 + lm][lq * 8];
    }
    #pragma unroll
    for (int ni = 0; ni < 4; ++ni) {
      bh[ni] = *(const bf16x8*)&Bh[wx + ni * 16 + lm][lq * 8];
      bl[ni] = *(const bf16x8*)&Bl[wx + ni * 16 + lm][lq * 8];
    }
    #pragma unroll
    for (int mi = 0; mi < 4; ++mi)
      #pragma unroll
      for (int ni = 0; ni < 4; ++ni) {
        acc[mi][ni] = __builtin_amdgcn_mfma_f32_16x16x32_bf16(ah[mi], bh[ni], acc[mi][ni], 0, 0, 0);
        acc[mi][ni] = __builtin_amdgcn_mfma_f32_16x16x32_bf16(ah[mi], bl[ni], acc[mi][ni], 0, 0, 0);
        acc[mi][ni] = __builtin_amdgcn_mfma_f32_16x16x32_bf16(al[mi], bh[ni], acc[mi][ni], 0, 0, 0);
      }
    __syncthreads();
  }

  #pragma unroll
  for (int ni = 0; ni < 4; ++ni) {
    int col = n0 + wx + ni * 16 + lm;
    float bb = bias[col];
    #pragma unroll
    for (int mi = 0; mi < 4; ++mi) {
      int rbase = m0 + wy + mi * 16 + lq * 4;
      #pragma unroll
      for (int r = 0; r < 4; ++r)
        C[(size_t)(rbase + r) * Nn + col] = acc[mi][ni][r] + bb;
    }
  }
}

// ---------------------------------------------------------------------------
// slot-GEMM device helper for the cooperative kernel.
// Computes out[b0..b0+32, jx*64..+64] = act(in @ W^T + bias) with 32 input
// rows staged in LDS. Block = 256 thr = 4 groups x 64 j-lanes; each thread
// 8 batch rows (LDS reads are wave-broadcast, conflict-free).
template<int K, int ACT>
__device__ void dev_gemm_slot(const float* __restrict__ in, long istride,
                              const float* __restrict__ W, const float* __restrict__ bias,
                              float* __restrict__ out, int J, int slot, float* lds) {
  const int nx = J >> 6;
  const int x = slot % nx, y = slot / nx;
  const int b0 = y * 32;
  const int tid = threadIdx.x;
  const int j = x * 64 + (tid & 63);
  const int g = tid >> 6;

  for (int r = g; r < 32; r += 4) {
    const float4* src = (const float4*)(in + (size_t)(b0 + r) * istride);
    float4* dst = (float4*)(lds + (size_t)r * K);
    #pragma unroll 4
    for (int idx = tid & 63; idx < K / 4; idx += 64) dst[idx] = src[idx];
  }
  __syncthreads();

  const float4* w4 = (const float4*)(W + (size_t)j * K);
  float acc[8];
  #pragma unroll
  for (int r = 0; r < 8; ++r) acc[r] = 0.f;
  const float* base = lds + (size_t)g * 8 * K;

  for (int k4 = 0; k4 < K / 4; ++k4) {
    float4 wv = w4[k4];
    #pragma unroll
    for (int r = 0; r < 8; ++r) {
      float4 xv = *(const float4*)(base + (size_t)r * K + k4 * 4);
      acc[r] += wv.x * xv.x + wv.y * xv.y + wv.z * xv.z + wv.w * xv.w;
    }
  }
  float bb = bias[j];
  #pragma unroll
  for (int r = 0; r < 8; ++r) {
    float v = acc[r] + bb;
    if (ACT) v = tanhf(v);
    out[(size_t)(b0 + g * 8 + r) * J + j] = v;
  }
  __syncthreads();
}

// ---------------------------------------------------------------------------
// Cooperative kernel: h0 + full T-step recurrence. 256 blocks x 256 threads,
// 128 KB LDS -> exactly 1 block/CU (co-residency guaranteed).
__launch_bounds__(256)
__global__ void k_coop(const float* __restrict__ sent, const float* __restrict__ h0_w,
                       const float* __restrict__ h0_b, const float* __restrict__ w_ih,
                       const float* __restrict__ w_hh, const float* __restrict__ b_ih,
                       const float* __restrict__ b_hh, const float* __restrict__ wq,
                       const float* __restrict__ bq, const float* __restrict__ wsv,
                       const float* __restrict__ bsv, const float* __restrict__ dproj,
                       float* __restrict__ h, float* __restrict__ s_row,
                       float* __restrict__ gx, float* __restrict__ gh,
                       float* __restrict__ q, float* __restrict__ scoresf,
                       int* __restrict__ mask, float* __restrict__ outScores,
                       float* __restrict__ outSel) {
  cg::grid_group grid = cg::this_grid();
  __shared__ float lds[32 * 1024];               // 128 KB
  __shared__ int s_idx;
  const int blk = blockIdx.x, tid = threadIdx.x;

  // ---- phase 0: h0 = tanh(sent[:,0,512:] @ h0_w^T + h0_b); zero s_row, mask
  if (blk < 32) {
    dev_gemm_slot<512, 1>(sent + 512, (long)Ln * D2n, h0_w, h0_b, h, 512, blk, lds);
  } else {
    int g0 = (blk - 32) * 256 + tid;
    for (int i = g0; i < Bn * D2n; i += 224 * 256) s_row[i] = 0.f;
    for (int i = g0; i < Bn * Ln; i += 224 * 256) mask[i] = 0;
  }
  grid.sync();

  for (int t = 0; t < Tn; ++t) {
    // ---- A: gx = s_prev @ w_ih^T + b_ih (96 slots), gh = h @ w_hh^T + b_hh (96)
    if (blk < 96)
      dev_gemm_slot<1024, 0>(s_row, 1024, w_ih, b_ih, gx, G3n, blk, lds);
    else if (blk < 192)
      dev_gemm_slot<512, 0>(h, 512, w_hh, b_hh, gh, G3n, blk - 96, lds);
    grid.sync();

    // ---- B: GRU pointwise h = (1-z)*n + z*h
    {
      int i = blk * 256 + tid;                   // 65536 exactly
      int b = i >> 9, j = i & 511;
      const float* gxb = gx + (size_t)b * G3n;
      const float* ghb = gh + (size_t)b * G3n;
      float rg = 1.f / (1.f + __expf(-(gxb[j] + ghb[j])));
      float zg = 1.f / (1.f + __expf(-(gxb[512 + j] + ghb[512 + j])));
      float ng = tanhf(gxb[1024 + j] + rg * ghb[1024 + j]);
      h[i] = (1.f - zg) * ng + zg * h[i];
    }
    grid.sync();

    // ---- C: q = h @ wq^T + bq (32 slots)
    if (blk < 32)
      dev_gemm_slot<512, 0>(h, 512, wq, bq, q, 512, blk, lds);
    grid.sync();

    // ---- D1: scores (block = (b, half); 4 waves x 25 rows)
    {
      int b = blk >> 1, half = blk & 1;
      int w = tid >> 6, lane = tid & 63;
      const float4* q4  = (const float4*)(q + (size_t)b * Nn);
      const float4* ws4 = (const float4*)wsv;
      float4 q0 = q4[lane], q1 = q4[lane + 64];
      float4 w0 = ws4[lane], w1 = ws4[lane + 64];
      float bsv0 = bsv[0];
      for (int l = half * 100 + w; l < half * 100 + 100; l += 4) {
        const float4* dp4 = (const float4*)(dproj + ((size_t)b * Ln + l) * Nn);
        float4 d0 = dp4[lane], d1 = dp4[lane + 64];
        float sum = fast_tanh(q0.x + d0.x) * w0.x + fast_tanh(q0.y + d0.y) * w0.y
                  + fast_tanh(q0.z + d0.z) * w0.z + fast_tanh(q0.w + d0.w) * w0.w
                  + fast_tanh(q1.x + d1.x) * w1.x + fast_tanh(q1.y + d1.y) * w1.y
                  + fast_tanh(q1.z + d1.z) * w1.z + fast_tanh(q1.w + d1.w) * w1.w;
        #pragma unroll
        for (int off = 32; off > 0; off >>= 1) sum += __shfl_xor(sum, off, 64);
        if (lane == 0) {
          float v = sum + bsv0;
          if (mask[b * Ln + l]) v = -1000000.0f;
          scoresf[b * Ln + l] = v;
          outScores[(size_t)b * (Tn * Ln) + t * Ln + l] = v;
        }
      }
    }
    grid.sync();

    // ---- D2: per-batch argmax (first-index ties), mask update, gather
    if (blk < Bn) {
      int b = blk;
      if (tid < 64) {
        const float* sc = scoresf + (size_t)b * Ln;
        float best = -3.0e38f; int bi = 0;
        for (int l = tid; l < Ln; l += 64) {
          float v = sc[l];
          if (v > best) { best = v; bi = l; }
        }
        #pragma unroll
        for (int off = 32; off > 0; off >>= 1) {
          float ov = __shfl_down(best, off, 64);
          int   oi = __shfl_down(bi,   off, 64);
          if (ov > best || (ov == best && oi < bi)) { best = ov; bi = oi; }
        }
        if (tid == 0) s_idx = bi;
      }
      __syncthreads();
      int idx = s_idx;
      const float* src = sent + ((size_t)b * Ln + idx) * D2n;
      float* dstp = s_row + (size_t)b * D2n;
      *(float4*)(dstp + tid * 4) = *(const float4*)(src + tid * 4);
      if (tid == 0) {
        mask[b * Ln + idx] = 1;
        outSel[(size_t)b * Tn + t] = (float)idx;
      }
      __syncthreads();
    }
    grid.sync();
  }
}

// ---------------------------------------------------------------------------
extern "C" void kernel_launch(void* const* d_in, const int* in_sizes, int n_in,
                              void* d_out, int out_size, void* d_ws, size_t ws_size,
                              hipStream_t stream) {
  const float* sent = (const float*)d_in[0];
  const float* h0_w = (const float*)d_in[1];
  const float* h0_b = (const float*)d_in[2];
  const float* w_ih = (const float*)d_in[3];
  const float* w_hh = (const float*)d_in[4];
  const float* b_ih = (const float*)d_in[5];
  const float* b_hh = (const float*)d_in[6];
  const float* wq   = (const float*)d_in[7];
  const float* bq   = (const float*)d_in[8];
  const float* wd   = (const float*)d_in[9];
  const float* bd   = (const float*)d_in[10];
  const float* wsv  = (const float*)d_in[11];
  const float* bsv  = (const float*)d_in[12];

  float* wsf     = (float*)d_ws;
  float* d_proj  = wsf;                       // 25600*512
  float* s_row   = d_proj + 13107200;         // 128*1024
  float* h       = s_row + 131072;            // 128*512
  float* gx      = h + 65536;                 // 128*1536
  float* gh      = gx + 196608;               // 128*1536
  float* q       = gh + 196608;               // 128*512
  float* scoresf = q + 65536;                 // 128*200
  int*   mask    = (int*)(scoresf + 25600);   // 128*200
  ushort* Whi    = (ushort*)(mask + 25600);   // 512*1024
  ushort* Wlo    = Whi + 524288;              // 512*1024

  float* outScores = (float*)d_out;                       // (B, T, L) fp32
  float* outSel    = outScores + (size_t)Bn * Tn * Ln;    // (B, T) fp32

  k_splitW<<<512, 256, 0, stream>>>(wd, Whi, Wlo);
  k_dproj_mfma<<<dim3(200, 4), 256, 0, stream>>>(sent, Whi, Wlo, bd, d_proj);

  void* args[] = {
    (void*)&sent, (void*)&h0_w, (void*)&h0_b, (void*)&w_ih, (void*)&w_hh,
    (void*)&b_ih, (void*)&b_hh, (void*)&wq, (void*)&bq, (void*)&wsv,
    (void*)&bsv, (void*)&d_proj, (void*)&h, (void*)&s_row, (void*)&gx,
    (void*)&gh, (void*)&q, (void*)&scoresf, (void*)&mask,
    (void*)&outScores, (void*)&outSel
  };
  hipLaunchCooperativeKernel((void*)k_coop, dim3(256), dim3(256), args, 0, stream);
}

// Round 7
// 625.159 us; speedup vs baseline: 1.6441x; 1.6441x over previous
//
#include <hip/hip_runtime.h>
#include <hip/hip_bf16.h>

// Problem constants
constexpr int Bn  = 128;   // batch
constexpr int Ln  = 200;   // sentences
constexpr int D2n = 1024;  // 2*SH
constexpr int G3n = 1536;  // 3*EH
constexpr int Tn  = 3;
constexpr int Nn  = 512;   // A (attention dim) == d_proj cols
constexpr int Kn  = 1024;  // d_proj K

typedef unsigned short ushort;
typedef float f32x4 __attribute__((ext_vector_type(4)));
typedef __bf16 bf16x8 __attribute__((ext_vector_type(8)));

// weight-split offsets (elements) inside Whi/Wlo: [wd | w_ih | w_hh]
constexpr size_t OFF_WD = 0;
constexpr size_t OFF_IH = 524288;      // 512*1024
constexpr size_t OFF_HH = 2097152;     // + 1536*1024
constexpr size_t W_TOT  = 2883584;     // + 1536*512

__device__ __forceinline__ ushort f2bf(float f) {   // RNE float->bf16
  unsigned u = __float_as_uint(f);
  unsigned r = (u + 0x7fffu + ((u >> 16) & 1u)) >> 16;
  return (ushort)r;
}
__device__ __forceinline__ float bf2f(ushort h) {
  return __uint_as_float(((unsigned)h) << 16);
}
// truncation split: f = hi + lo with |err| <= 2^-16 |f|
__device__ __forceinline__ void tsplit(float f, ushort& hi, ushort& lo) {
  unsigned u = __float_as_uint(f);
  hi = (ushort)(u >> 16);
  lo = (ushort)(__float_as_uint(f - __uint_as_float(u & 0xffff0000u)) >> 16);
}
__device__ __forceinline__ float fast_tanh(float x) {
  float ax = __builtin_fabsf(x);
  float e  = __expf(-2.f * ax);
  float t  = (1.f - e) / (1.f + e);
  return __builtin_copysignf(t, x);
}

// ---------------------------------------------------------------------------
// split wd, w_ih, w_hh (fp32) into hi/lo bf16 (RNE), one kernel
__global__ void k_split_all(const float* __restrict__ wd, const float* __restrict__ w_ih,
                            const float* __restrict__ w_hh, ushort* __restrict__ hi,
                            ushort* __restrict__ lo) {
  size_t i = (size_t)blockIdx.x * 256 + threadIdx.x;   // float4 index, 720896 total
  size_t e = i * 4;
  const float* src;
  if (e < OFF_IH)       src = wd + e;
  else if (e < OFF_HH)  src = w_ih + (e - OFF_IH);
  else                  src = w_hh + (e - OFF_HH);
  float4 v = *(const float4*)src;
  ushort4 h, l;
  h.x = f2bf(v.x); l.x = f2bf(v.x - bf2f(h.x));
  h.y = f2bf(v.y); l.y = f2bf(v.y - bf2f(h.y));
  h.z = f2bf(v.z); l.z = f2bf(v.z - bf2f(h.z));
  h.w = f2bf(v.w); l.w = f2bf(v.w - bf2f(h.w));
  ((ushort4*)hi)[i] = h;
  ((ushort4*)lo)[i] = l;
}

// ---------------------------------------------------------------------------
// h0 = tanh(sent[:,0,512:] @ h0_w^T + h0_b), write h as hi/lo split.
// Also zero-inits s_prev splits and mask (replaces memsets).
// One block per batch, 256 threads.
__launch_bounds__(256)
__global__ void k_h0(const float* __restrict__ sent, const float* __restrict__ h0_w,
                     const float* __restrict__ h0_b, ushort* __restrict__ h_hi,
                     ushort* __restrict__ h_lo, ushort* __restrict__ s_hi,
                     ushort* __restrict__ s_lo, int* __restrict__ mask) {
  const int b = blockIdx.x, tid = threadIdx.x;
  __shared__ float ls[512];
  ls[tid]       = sent[(size_t)b * (Ln * D2n) + 512 + tid];
  ls[tid + 256] = sent[(size_t)b * (Ln * D2n) + 768 + tid];
  // zero s_prev splits (1024 ushorts each) and mask (200 ints)
  ushort4 z4 = {0, 0, 0, 0};
  ((ushort4*)(s_hi + (size_t)b * D2n))[tid] = z4;
  ((ushort4*)(s_lo + (size_t)b * D2n))[tid] = z4;
  if (tid < Ln) mask[b * Ln + tid] = 0;
  __syncthreads();

  #pragma unroll
  for (int jj = 0; jj < 2; ++jj) {
    int j = tid + jj * 256;
    const float4* wrow = (const float4*)(h0_w + (size_t)j * 512);
    float acc = 0.f;
    for (int k4 = 0; k4 < 128; ++k4) {
      float4 wv = wrow[k4];
      float4 hv = *(const float4*)&ls[k4 * 4];   // uniform addr -> broadcast
      acc += wv.x * hv.x + wv.y * hv.y + wv.z * hv.z + wv.w * hv.w;
    }
    float v = tanhf(acc + h0_b[j]);
    ushort hh, ll; tsplit(v, hh, ll);
    h_hi[(size_t)b * 512 + j] = hh;
    h_lo[(size_t)b * 512 + j] = ll;
  }
}

// ---------------------------------------------------------------------------
// d_proj = sent @ wd^T + bd  via split-bf16 MFMA (unchanged, proven 145 us)
constexpr int LDW = 36;
__launch_bounds__(256)
__global__ void k_dproj_mfma(const float* __restrict__ A, const ushort* __restrict__ Whi,
                             const ushort* __restrict__ Wlo, const float* __restrict__ bias,
                             float* __restrict__ C) {
  __shared__ __align__(16) ushort Ah[128][LDW];
  __shared__ __align__(16) ushort Al[128][LDW];
  __shared__ __align__(16) ushort Bh[128][LDW];
  __shared__ __align__(16) ushort Bl[128][LDW];

  const int m0 = blockIdx.x * 128, n0 = blockIdx.y * 128;
  const int tid  = threadIdx.x;
  const int wave = tid >> 6, lane = tid & 63;
  const int wy = (wave >> 1) * 64, wx = (wave & 1) * 64;
  const int lm = lane & 15, lq = lane >> 4;
  const int sr = tid >> 1;
  const int sk = (tid & 1) * 16;

  f32x4 acc[4][4] = {};

  const float* Arow = A + (size_t)(m0 + sr) * Kn + sk;
  const ushort* Bhrow = Whi + (size_t)(n0 + sr) * Kn + sk;
  const ushort* Blrow = Wlo + (size_t)(n0 + sr) * Kn + sk;

  for (int k0 = 0; k0 < Kn; k0 += 32) {
    #pragma unroll
    for (int i = 0; i < 4; ++i) {
      float4 v = *(const float4*)(Arow + k0 + i * 4);
      ushort4 h, l;
      tsplit(v.x, h.x, l.x); tsplit(v.y, h.y, l.y);
      tsplit(v.z, h.z, l.z); tsplit(v.w, h.w, l.w);
      *(ushort4*)&Ah[sr][sk + i * 4] = h;
      *(ushort4*)&Al[sr][sk + i * 4] = l;
    }
    #pragma unroll
    for (int i = 0; i < 2; ++i) {
      *(int4*)&Bh[sr][sk + i * 8] = *(const int4*)(Bhrow + k0 + i * 8);
      *(int4*)&Bl[sr][sk + i * 8] = *(const int4*)(Blrow + k0 + i * 8);
    }
    __syncthreads();

    bf16x8 ah[4], al[4], bh[4], bl[4];
    #pragma unroll
    for (int mi = 0; mi < 4; ++mi) {
      ah[mi] = *(const bf16x8*)&Ah[wy + mi * 16 + lm][lq * 8];
      al[mi] = *(const bf16x8*)&Al[wy + mi * 16 + lm][lq * 8];
    }
    #pragma unroll
    for (int ni = 0; ni < 4; ++ni) {
      bh[ni] = *(const bf16x8*)&Bh[wx + ni * 16 + lm][lq * 8];
      bl[ni] = *(const bf16x8*)&Bl[wx + ni * 16 + lm][lq * 8];
    }
    #pragma unroll
    for (int mi = 0; mi < 4; ++mi)
      #pragma unroll
      for (int ni = 0; ni < 4; ++ni) {
        acc[mi][ni] = __builtin_amdgcn_mfma_f32_16x16x32_bf16(ah[mi], bh[ni], acc[mi][ni], 0, 0, 0);
        acc[mi][ni] = __builtin_amdgcn_mfma_f32_16x16x32_bf16(ah[mi], bl[ni], acc[mi][ni], 0, 0, 0);
        acc[mi][ni] = __builtin_amdgcn_mfma_f32_16x16x32_bf16(al[mi], bh[ni], acc[mi][ni], 0, 0, 0);
      }
    __syncthreads();
  }

  #pragma unroll
  for (int ni = 0; ni < 4; ++ni) {
    int col = n0 + wx + ni * 16 + lm;
    float bb = bias[col];
    #pragma unroll
    for (int mi = 0; mi < 4; ++mi) {
      int rbase = m0 + wy + mi * 16 + lq * 4;
      #pragma unroll
      for (int r = 0; r < 4; ++r)
        C[(size_t)(rbase + r) * Nn + col] = acc[mi][ni][r] + bb;
    }
  }
}

// ---------------------------------------------------------------------------
// gx = s_prev @ w_ih^T + b_ih  (blockIdx.y==0, K=1024)
// gh = h      @ w_hh^T + b_hh  (blockIdx.y==1, K=512)
// A from pre-split hi/lo bf16 arrays. M=128 (one tile), N=1536 (12 x-blocks).
__launch_bounds__(256)
__global__ void k_gxgh(const ushort* __restrict__ s_hi, const ushort* __restrict__ s_lo,
                       const ushort* __restrict__ h_hi, const ushort* __restrict__ h_lo,
                       const ushort* __restrict__ Whi, const ushort* __restrict__ Wlo,
                       const float* __restrict__ b_ih, const float* __restrict__ b_hh,
                       float* __restrict__ gx, float* __restrict__ gh) {
  __shared__ __align__(16) ushort Ah[128][LDW];
  __shared__ __align__(16) ushort Al[128][LDW];
  __shared__ __align__(16) ushort Bh[128][LDW];
  __shared__ __align__(16) ushort Bl[128][LDW];

  const int n0 = blockIdx.x * 128;
  const int K    = blockIdx.y == 0 ? 1024 : 512;
  const ushort* Ahg = blockIdx.y == 0 ? s_hi : h_hi;
  const ushort* Alg = blockIdx.y == 0 ? s_lo : h_lo;
  const ushort* Whg = Whi + (blockIdx.y == 0 ? OFF_IH : OFF_HH);
  const ushort* Wlg = Wlo + (blockIdx.y == 0 ? OFF_IH : OFF_HH);
  const float*  bias = blockIdx.y == 0 ? b_ih : b_hh;
  float* out = blockIdx.y == 0 ? gx : gh;

  const int tid  = threadIdx.x;
  const int wave = tid >> 6, lane = tid & 63;
  const int wy = (wave >> 1) * 64, wx = (wave & 1) * 64;
  const int lm = lane & 15, lq = lane >> 4;
  const int sr = tid >> 1;
  const int sk = (tid & 1) * 16;

  f32x4 acc[4][4] = {};

  const ushort* Ahrow = Ahg + (size_t)sr * K + sk;
  const ushort* Alrow = Alg + (size_t)sr * K + sk;
  const ushort* Bhrow = Whg + (size_t)(n0 + sr) * K + sk;
  const ushort* Blrow = Wlg + (size_t)(n0 + sr) * K + sk;

  for (int k0 = 0; k0 < K; k0 += 32) {
    #pragma unroll
    for (int i = 0; i < 2; ++i) {
      *(int4*)&Ah[sr][sk + i * 8] = *(const int4*)(Ahrow + k0 + i * 8);
      *(int4*)&Al[sr][sk + i * 8] = *(const int4*)(Alrow + k0 + i * 8);
      *(int4*)&Bh[sr][sk + i * 8] = *(const int4*)(Bhrow + k0 + i * 8);
      *(int4*)&Bl[sr][sk + i * 8] = *(const int4*)(Blrow + k0 + i * 8);
    }
    __syncthreads();

    bf16x8 ah[4], al[4], bh[4], bl[4];
    #pragma unroll
    for (int mi = 0; mi < 4; ++mi) {
      ah[mi] = *(const bf16x8*)&Ah[wy + mi * 16 + lm][lq * 8];
      al[mi] = *(const bf16x8*)&Al[wy + mi * 16 + lm][lq * 8];
    }
    #pragma unroll
    for (int ni = 0; ni < 4; ++ni) {
      bh[ni] = *(const bf16x8*)&Bh[wx + ni * 16 + lm][lq * 8];
      bl[ni] = *(const bf16x8*)&Bl[wx + ni * 16 + lm][lq * 8];
    }
    #pragma unroll
    for (int mi = 0; mi < 4; ++mi)
      #pragma unroll
      for (int ni = 0; ni < 4; ++ni) {
        acc[mi][ni] = __builtin_amdgcn_mfma_f32_16x16x32_bf16(ah[mi], bh[ni], acc[mi][ni], 0, 0, 0);
        acc[mi][ni] = __builtin_amdgcn_mfma_f32_16x16x32_bf16(ah[mi], bl[ni], acc[mi][ni], 0, 0, 0);
        acc[mi][ni] = __builtin_amdgcn_mfma_f32_16x16x32_bf16(al[mi], bh[ni], acc[mi][ni], 0, 0, 0);
      }
    __syncthreads();
  }

  #pragma unroll
  for (int ni = 0; ni < 4; ++ni) {
    int col = n0 + wx + ni * 16 + lm;
    float bb = bias[col];
    #pragma unroll
    for (int mi = 0; mi < 4; ++mi) {
      int rbase = wy + mi * 16 + lq * 4;
      #pragma unroll
      for (int r = 0; r < 4; ++r)
        out[(size_t)(rbase + r) * G3n + col] = acc[mi][ni][r] + bb;
    }
  }
}

// ---------------------------------------------------------------------------
// Fused per-batch step: GRU pointwise -> q -> score -> argmax -> gather.
// One block (512 thr) per batch; all deps block-local.
__launch_bounds__(512)
__global__ void k_score_all(const float* __restrict__ gx, const float* __restrict__ gh,
                            ushort* __restrict__ h_hi, ushort* __restrict__ h_lo,
                            const float* __restrict__ wq, const float* __restrict__ bq,
                            const float* __restrict__ wsv, const float* __restrict__ bsv,
                            const float* __restrict__ dproj, const float* __restrict__ sent,
                            int* __restrict__ mask, ushort* __restrict__ s_hi,
                            ushort* __restrict__ s_lo, float* __restrict__ outScores,
                            float* __restrict__ outSel, int t) {
  const int b = blockIdx.x, tid = threadIdx.x;
  __shared__ float hs[512], qs[512], sc[Ln];
  __shared__ int s_idx;

  // ---- GRU pointwise (j = tid)
  {
    int j = tid;
    const float* gxb = gx + (size_t)b * G3n;
    const float* ghb = gh + (size_t)b * G3n;
    float hold = bf2f(h_hi[(size_t)b * 512 + j]) + bf2f(h_lo[(size_t)b * 512 + j]);
    float rg = 1.f / (1.f + __expf(-(gxb[j] + ghb[j])));
    float zg = 1.f / (1.f + __expf(-(gxb[512 + j] + ghb[512 + j])));
    float ng = tanhf(gxb[1024 + j] + rg * ghb[1024 + j]);
    float hn = (1.f - zg) * ng + zg * hold;
    hs[j] = hn;
    ushort hh, ll; tsplit(hn, hh, ll);
    h_hi[(size_t)b * 512 + j] = hh;
    h_lo[(size_t)b * 512 + j] = ll;
  }
  __syncthreads();

  // ---- q[j] = hs . wq[j,:] + bq[j]   (j = tid)
  {
    int j = tid;
    const float4* wrow = (const float4*)(wq + (size_t)j * 512);
    float acc = 0.f;
    for (int k4 = 0; k4 < 128; ++k4) {
      float4 wv = wrow[k4];
      float4 hv = *(const float4*)&hs[k4 * 4];   // uniform addr -> broadcast
      acc += wv.x * hv.x + wv.y * hv.y + wv.z * hv.z + wv.w * hv.w;
    }
    qs[j] = acc + bq[j];
  }
  __syncthreads();

  // ---- scores: 8 waves, wave w handles l = w, w+8, ...
  {
    int w = tid >> 6, lane = tid & 63;
    const float4* ws4 = (const float4*)wsv;
    float4 q0 = *(const float4*)&qs[lane * 4];
    float4 q1 = *(const float4*)&qs[(lane + 64) * 4];
    float4 w0 = ws4[lane], w1 = ws4[lane + 64];
    float bs0 = bsv[0];
    for (int l = w; l < Ln; l += 8) {
      const float4* dp4 = (const float4*)(dproj + ((size_t)b * Ln + l) * Nn);
      float4 d0 = dp4[lane], d1 = dp4[lane + 64];
      float sum = fast_tanh(q0.x + d0.x) * w0.x + fast_tanh(q0.y + d0.y) * w0.y
                + fast_tanh(q0.z + d0.z) * w0.z + fast_tanh(q0.w + d0.w) * w0.w
                + fast_tanh(q1.x + d1.x) * w1.x + fast_tanh(q1.y + d1.y) * w1.y
                + fast_tanh(q1.z + d1.z) * w1.z + fast_tanh(q1.w + d1.w) * w1.w;
      #pragma unroll
      for (int off = 32; off > 0; off >>= 1) sum += __shfl_xor(sum, off, 64);
      if (lane == 0) {
        float v = sum + bs0;
        if (mask[b * Ln + l]) v = -1000000.0f;
        sc[l] = v;
        outScores[(size_t)b * (Tn * Ln) + t * Ln + l] = v;
      }
    }
  }
  __syncthreads();

  // ---- argmax (first-index tie-break), wave 0
  if (tid < 64) {
    float best = -3.0e38f; int bi = 0;
    for (int l = tid; l < Ln; l += 64) {
      float v = sc[l];
      if (v > best) { best = v; bi = l; }
    }
    #pragma unroll
    for (int off = 32; off > 0; off >>= 1) {
      float ov = __shfl_down(best, off, 64);
      int   oi = __shfl_down(bi,   off, 64);
      if (ov > best || (ov == best && oi < bi)) { best = ov; bi = oi; }
    }
    if (tid == 0) s_idx = bi;
  }
  __syncthreads();

  // ---- gather selected sentence -> s_prev (split), update mask, outSel
  int idx = s_idx;
  {
    const float* src = sent + ((size_t)b * Ln + idx) * D2n;
    int k = tid * 2;                               // 512 thr x 2 = 1024
    float2 v = *(const float2*)(src + k);
    ushort hx, lx, hy, ly;
    tsplit(v.x, hx, lx); tsplit(v.y, hy, ly);
    ushort2 hh = {hx, hy}, ll = {lx, ly};
    *(ushort2*)(s_hi + (size_t)b * D2n + k) = hh;
    *(ushort2*)(s_lo + (size_t)b * D2n + k) = ll;
  }
  if (tid == 0) {
    mask[b * Ln + idx] = 1;
    outSel[(size_t)b * Tn + t] = (float)idx;
  }
}

// ---------------------------------------------------------------------------
extern "C" void kernel_launch(void* const* d_in, const int* in_sizes, int n_in,
                              void* d_out, int out_size, void* d_ws, size_t ws_size,
                              hipStream_t stream) {
  const float* sent = (const float*)d_in[0];
  const float* h0_w = (const float*)d_in[1];
  const float* h0_b = (const float*)d_in[2];
  const float* w_ih = (const float*)d_in[3];
  const float* w_hh = (const float*)d_in[4];
  const float* b_ih = (const float*)d_in[5];
  const float* b_hh = (const float*)d_in[6];
  const float* wq   = (const float*)d_in[7];
  const float* bq   = (const float*)d_in[8];
  const float* wd   = (const float*)d_in[9];
  const float* bd   = (const float*)d_in[10];
  const float* wsv  = (const float*)d_in[11];
  const float* bsv  = (const float*)d_in[12];

  float* wsf     = (float*)d_ws;
  float* d_proj  = wsf;                       // 25600*512 floats
  float* gx      = d_proj + 13107200;         // 128*1536
  float* gh      = gx + 196608;               // 128*1536
  int*   mask    = (int*)(gh + 196608);       // 128*200
  ushort* h_hi   = (ushort*)(mask + 25600);   // 128*512
  ushort* h_lo   = h_hi + 65536;
  ushort* s_hi   = h_lo + 65536;              // 128*1024
  ushort* s_lo   = s_hi + 131072;
  ushort* Whi    = s_lo + 131072;             // 2883584
  ushort* Wlo    = Whi + W_TOT;

  float* outScores = (float*)d_out;                       // (B, T, L) fp32
  float* outSel    = outScores + (size_t)Bn * Tn * Ln;    // (B, T) fp32

  k_split_all<<<2816, 256, 0, stream>>>(wd, w_ih, w_hh, Whi, Wlo);
  k_h0<<<128, 256, 0, stream>>>(sent, h0_w, h0_b, h_hi, h_lo, s_hi, s_lo, mask);
  k_dproj_mfma<<<dim3(200, 4), 256, 0, stream>>>(sent, Whi + OFF_WD, Wlo + OFF_WD, bd, d_proj);

  for (int t = 0; t < Tn; ++t) {
    k_gxgh<<<dim3(12, 2), 256, 0, stream>>>(s_hi, s_lo, h_hi, h_lo, Whi, Wlo,
                                            b_ih, b_hh, gx, gh);
    k_score_all<<<128, 512, 0, stream>>>(gx, gh, h_hi, h_lo, wq, bq, wsv, bsv,
                                         d_proj, sent, mask, s_hi, s_lo,
                                         outScores, outSel, t);
  }
}